// Round 1
// 1275.997 us; speedup vs baseline: 1.5385x; 1.5385x over previous
//
#include <hip/hip_runtime.h>
#include <hip/hip_bf16.h>
#include <stdint.h>

// HierarchicalGNN forward, FP32 in/out, MFMA bf16 GEMMs, CSR-gather GAT (no f32 atomics).
// h=relu(x@Wp+bp); two GATConv(+selfloops, softmax-per-dst) -> LN -> relu;
// concat @ Wf -> LN -> L2-normalize.
// N=200000, E=200000/dir, IN=HID=256, HEADS=4, C=64, OUT=128.

typedef __attribute__((ext_vector_type(8))) short bf16x8;
typedef __attribute__((ext_vector_type(4))) short bf16x4;
typedef __attribute__((ext_vector_type(4))) float f32x4;

#define HID 256
#define HEADS 4
#define CH 64

__device__ __forceinline__ float wred(float v) {
    #pragma unroll
    for (int o = 32; o > 0; o >>= 1) v += __shfl_xor(v, o, 64);
    return v;
}
__device__ __forceinline__ float wredmax(float v) {
    #pragma unroll
    for (int o = 32; o > 0; o >>= 1) v = fmaxf(v, __shfl_xor(v, o, 64));
    return v;
}
__device__ __forceinline__ float bf2f(short s) {
    return __uint_as_float(((unsigned)(unsigned short)s) << 16);
}
__device__ __forceinline__ float sel4(float a0, float a1, float a2, float a3, int h) {
    return h == 0 ? a0 : (h == 1 ? a1 : (h == 2 ? a2 : a3));
}

// async global->LDS, 16B per lane (global_load_lds_dwordx4). LDS dest must be
// linear: wave-uniform base + lane*16 (we pass the per-lane pointer whose
// lane-0 value is the wave base; HW adds lane*16 itself).
__device__ __forceinline__ void gload_lds16(const void* g, void* l) {
    __builtin_amdgcn_global_load_lds(
        reinterpret_cast<const __attribute__((address_space(1))) uint32_t*>(
            reinterpret_cast<uintptr_t>(g)),
        reinterpret_cast<__attribute__((address_space(3))) uint32_t*>(
            reinterpret_cast<uintptr_t>(l)),
        16, 0, 0);
}

// ---------------- f32 -> bf16 convert ----------------
__global__ __launch_bounds__(256) void cvt_bf16(const float* __restrict__ src,
                                                __hip_bfloat16* __restrict__ dst, long n) {
    long i = (long)blockIdx.x * 256 + threadIdx.x;
    if (i < n) dst[i] = __float2bfloat16(src[i]);
}

// ---------------- transpose+convert W[KI,KO] f32 -> Wt[KO,KI] bf16 ----------------
__global__ void transpose_w(const float* __restrict__ W,
                            __hip_bfloat16* __restrict__ Wt, int KI, int KO) {
    int idx = blockIdx.x * 256 + threadIdx.x;
    if (idx >= KI * KO) return;
    int k = idx / KO, j = idx % KO;
    Wt[(long)j * KI + k] = __float2bfloat16(W[idx]);
}

// ---------------- tiled MFMA GEMM: C[N,BN] = A[N,KI] @ Bt[BN,KI]^T ----------------
// m97 structure: BM=128, BK=32, LDS-staged A/B via global_load_lds_dwordx4,
// 2 barriers per K-step. BN = full output width (256 or 128) so A is fetched once.
// 512 threads = 8 waves; wave tile 64x64 (BN=256: 2x4 wave grid; BN=128: 4x2).
template<int BN>
__global__ __launch_bounds__(512) void gemm_tiled(
    const __hip_bfloat16* __restrict__ A0, const __hip_bfloat16* __restrict__ A1,
    int lda, int kSplit,
    const __hip_bfloat16* __restrict__ Bt, int KI,
    const float* __restrict__ bias, int doRelu,
    __hip_bfloat16* __restrict__ outB, float* __restrict__ outF, int N) {

    constexpr int WN = BN / 64;          // waves along N (4 or 2)
    constexpr int WM = 8 / WN;           // waves along M (2 or 4)
    constexpr int MR = (128 / WM) / 16;  // m-frags per wave (4 or 2)

    __shared__ __align__(16) __hip_bfloat16 sA[128 * 32];   // [row][k] 64B rows
    __shared__ __align__(16) __hip_bfloat16 sB[BN * 32];    // [col][k] 64B rows

    int tid = threadIdx.x;
    int wv = tid >> 6, ln = tid & 63;
    int m = ln & 15, q = ln >> 4;
    long row0 = (long)blockIdx.x * 128;
    int wr = (wv / WN) * (128 / WM);     // wave row base in tile
    int wc = (wv % WN) * 64;             // wave col base

    f32x4 acc[MR][4];
    #pragma unroll
    for (int mi = 0; mi < MR; ++mi)
        #pragma unroll
        for (int t = 0; t < 4; ++t) acc[mi][t] = (f32x4){0.f, 0.f, 0.f, 0.f};

    // staging geometry: byte o in tile; row = o>>6 (64B per row), kbyte = o&63
    int oA = tid * 16;                   // sA: 8192 B, one issue per thread
    long rowA = row0 + (oA >> 6);
    if (rowA >= N) rowA = N - 1;         // clamp tail loads (dup reads, safe)
    long aOff = rowA * lda + ((oA & 63) >> 1);

    for (int k0 = 0; k0 < KI; k0 += 32) {
        const __hip_bfloat16* Ab = (k0 < kSplit) ? A0 + k0 : A1 + (k0 - kSplit);
        __syncthreads();                 // prev compute done reading LDS
        gload_lds16(Ab + aOff, (char*)sA + oA);
        #pragma unroll
        for (int j = 0; j < BN / 128; ++j) {   // sB: BN*64 B -> 1 or 2 issues
            int o = j * 8192 + tid * 16;
            const __hip_bfloat16* src = Bt + (long)(o >> 6) * KI + k0 + ((o & 63) >> 1);
            gload_lds16(src, (char*)sB + o);
        }
        __syncthreads();                 // compiler drains vmcnt(0) before barrier

        bf16x8 af[MR], bfr[4];
        #pragma unroll
        for (int mi = 0; mi < MR; ++mi)
            af[mi] = *(const bf16x8*)((const char*)sA + ((wr + mi * 16 + m) << 6) + q * 16);
        #pragma unroll
        for (int t = 0; t < 4; ++t)
            bfr[t] = *(const bf16x8*)((const char*)sB + ((wc + t * 16 + m) << 6) + q * 16);
        #pragma unroll
        for (int mi = 0; mi < MR; ++mi)
            #pragma unroll
            for (int t = 0; t < 4; ++t)
                acc[mi][t] = __builtin_amdgcn_mfma_f32_16x16x32_bf16(af[mi], bfr[t],
                                                                     acc[mi][t], 0, 0, 0);
    }

    #pragma unroll
    for (int mi = 0; mi < MR; ++mi) {
        #pragma unroll
        for (int t = 0; t < 4; ++t) {
            int col = wc + t * 16 + m;
            float bv = bias ? bias[col] : 0.f;
            #pragma unroll
            for (int r = 0; r < 4; ++r) {
                long row = row0 + wr + mi * 16 + q * 4 + r;
                if (row < N) {
                    float v = acc[mi][t][r] + bv;
                    if (doRelu) v = fmaxf(v, 0.f);
                    if (outB) outB[row * BN + col] = __float2bfloat16(v);
                    else      outF[row * BN + col] = v;
                }
            }
        }
    }
}

// ---------------- attention scores: a_src/a_dst [N,4] ----------------
__global__ __launch_bounds__(256) void att_scores(
    const __hip_bfloat16* __restrict__ hw,
    const float* __restrict__ asrc, const float* __restrict__ adst,
    float* __restrict__ a_s, float* __restrict__ a_d, int N) {
    int lane = threadIdx.x & 63;
    long node = (long)blockIdx.x * 4 + (threadIdx.x >> 6);
    if (node >= N) return;
    const __hip_bfloat16* row = hw + node * HID;
    #pragma unroll
    for (int h = 0; h < HEADS; ++h) {
        float v = (float)row[h * CH + lane];
        float ps = v * asrc[h * CH + lane];
        float pd = v * adst[h * CH + lane];
        ps = wred(ps); pd = wred(pd);
        if (lane == 0) { a_s[node * 4 + h] = ps; a_d[node * 4 + h] = pd; }
    }
}

// ---------------- CSR build ----------------
__global__ __launch_bounds__(256) void hist_dst(const int* __restrict__ ei, int E,
                                                int* __restrict__ cnt) {
    int e = blockIdx.x * 256 + threadIdx.x;
    if (e < E) atomicAdd(&cnt[ei[E + e]], 1);
}

// exclusive scan within 256-chunks; bsum[b] = chunk total
__global__ __launch_bounds__(256) void scan1(const int* __restrict__ cnt,
                                             int* __restrict__ offpart,
                                             int* __restrict__ bsum, int n) {
    int t = threadIdx.x, i = blockIdx.x * 256 + t;
    int lane = t & 63, w = t >> 6;
    int v = (i < n) ? cnt[i] : 0;
    int inc = v;
    #pragma unroll
    for (int o = 1; o < 64; o <<= 1) {
        int u = __shfl_up(inc, o, 64);
        if (lane >= o) inc += u;
    }
    __shared__ int wsum[4];
    if (lane == 63) wsum[w] = inc;
    __syncthreads();
    int wadd = 0;
    #pragma unroll
    for (int k = 0; k < 4; ++k) if (k < w) wadd += wsum[k];
    if (i < n) offpart[i] = inc - v + wadd;
    if (t == 255) bsum[blockIdx.x] = inc + wadd;
}

// exclusive scan of up to 1024 block sums, single block of 256 threads
__global__ __launch_bounds__(256) void scan2(const int* __restrict__ bsum,
                                             int* __restrict__ btot, int nb) {
    int t = threadIdx.x, lane = t & 63, w = t >> 6;
    int loc[4]; int s = 0;
    #pragma unroll
    for (int k = 0; k < 4; ++k) {
        int idx = t * 4 + k;
        int v = (idx < nb) ? bsum[idx] : 0;
        loc[k] = s; s += v;
    }
    int inc = s;
    #pragma unroll
    for (int o = 1; o < 64; o <<= 1) {
        int u = __shfl_up(inc, o, 64);
        if (lane >= o) inc += u;
    }
    __shared__ int wsum[4];
    if (lane == 63) wsum[w] = inc;
    __syncthreads();
    int wadd = 0;
    #pragma unroll
    for (int k = 0; k < 4; ++k) if (k < w) wadd += wsum[k];
    int excl = inc - s + wadd;
    #pragma unroll
    for (int k = 0; k < 4; ++k) {
        int idx = t * 4 + k;
        if (idx < nb) btot[idx] = excl + loc[k];
    }
}

__global__ __launch_bounds__(256) void finalize_off(const int* __restrict__ offpart,
                                                    const int* __restrict__ btot,
                                                    int* __restrict__ off, int n, int E) {
    int i = blockIdx.x * 256 + threadIdx.x;
    if (i < n) off[i] = offpart[i] + btot[i >> 8];
    if (i == 0) off[n] = E;
}

__global__ __launch_bounds__(256) void scatter_src(const int* __restrict__ ei, int E,
                                                   const int* __restrict__ off,
                                                   int* __restrict__ cur,
                                                   int* __restrict__ esrc) {
    int e = blockIdx.x * 256 + threadIdx.x;
    if (e >= E) return;
    int d = ei[E + e];
    int pos = off[d] + atomicAdd(&cur[d], 1);
    esrc[pos] = ei[e];
}

// ---------------- fused GAT: softmax + gather + bias + LN + relu ----------------
// one wave per dst node; lane holds 4 contiguous channels c = lane*4..lane*4+3 (head = lane>>4).
__global__ __launch_bounds__(256) void gat_fused(
    const int* __restrict__ off, const int* __restrict__ esrc,
    const float* __restrict__ a_s, const float* __restrict__ a_d,
    const __hip_bfloat16* __restrict__ hw,
    const float* __restrict__ bias, const float* __restrict__ g,
    const float* __restrict__ b,
    __hip_bfloat16* __restrict__ out, int N) {
    int lane = threadIdx.x & 63;
    long d = (long)blockIdx.x * 4 + (threadIdx.x >> 6);
    if (d >= N) return;
    int beg = off[d], end = off[d + 1];
    f32x4 adv = *(const f32x4*)(a_d + 4 * d);
    f32x4 asd = *(const f32x4*)(a_s + 4 * d);
    float es0, es1, es2, es3;
    {
        float e;
        e = asd[0] + adv[0]; es0 = e > 0.f ? e : 0.2f * e;
        e = asd[1] + adv[1]; es1 = e > 0.f ? e : 0.2f * e;
        e = asd[2] + adv[2]; es2 = e > 0.f ? e : 0.2f * e;
        e = asd[3] + adv[3]; es3 = e > 0.f ? e : 0.2f * e;
    }
    // pass 1: per-head max over edges (lanes parallel over edges)
    float m0 = -3e38f, m1 = -3e38f, m2 = -3e38f, m3 = -3e38f;
    for (int j = beg + lane; j < end; j += 64) {
        int s = esrc[j];
        f32x4 asv = *(const f32x4*)(a_s + 4 * (long)s);
        float e;
        e = asv[0] + adv[0]; e = e > 0.f ? e : 0.2f * e; m0 = fmaxf(m0, e);
        e = asv[1] + adv[1]; e = e > 0.f ? e : 0.2f * e; m1 = fmaxf(m1, e);
        e = asv[2] + adv[2]; e = e > 0.f ? e : 0.2f * e; m2 = fmaxf(m2, e);
        e = asv[3] + adv[3]; e = e > 0.f ? e : 0.2f * e; m3 = fmaxf(m3, e);
    }
    m0 = fmaxf(wredmax(m0), es0); m1 = fmaxf(wredmax(m1), es1);
    m2 = fmaxf(wredmax(m2), es2); m3 = fmaxf(wredmax(m3), es3);
    // pass 2: per-head sum of exp
    float s0 = 0.f, s1 = 0.f, s2 = 0.f, s3 = 0.f;
    for (int j = beg + lane; j < end; j += 64) {
        int s = esrc[j];
        f32x4 asv = *(const f32x4*)(a_s + 4 * (long)s);
        float e;
        e = asv[0] + adv[0]; e = e > 0.f ? e : 0.2f * e; s0 += __expf(e - m0);
        e = asv[1] + adv[1]; e = e > 0.f ? e : 0.2f * e; s1 += __expf(e - m1);
        e = asv[2] + adv[2]; e = e > 0.f ? e : 0.2f * e; s2 += __expf(e - m2);
        e = asv[3] + adv[3]; e = e > 0.f ? e : 0.2f * e; s3 += __expf(e - m3);
    }
    s0 = wred(s0) + __expf(es0 - m0); s1 = wred(s1) + __expf(es1 - m1);
    s2 = wred(s2) + __expf(es2 - m2); s3 = wred(s3) + __expf(es3 - m3);
    // pass 3: alpha-weighted gather; lane's head
    int h4 = lane >> 4;
    int c0 = lane * 4;
    float mh = sel4(m0, m1, m2, m3, h4);
    float rsh = 1.f / sel4(s0, s1, s2, s3, h4);
    float adh = adv[h4];
    float acc0, acc1, acc2, acc3;
    {   // self loop
        float alpha = __expf(sel4(es0, es1, es2, es3, h4) - mh) * rsh;
        bf16x4 hv = *(const bf16x4*)(hw + d * HID + c0);
        acc0 = alpha * bf2f(hv[0]); acc1 = alpha * bf2f(hv[1]);
        acc2 = alpha * bf2f(hv[2]); acc3 = alpha * bf2f(hv[3]);
    }
    for (int j = beg; j < end; ++j) {
        int s = esrc[j];                       // uniform across wave
        float as_h = a_s[4 * (long)s + h4];
        float e = as_h + adh; e = e > 0.f ? e : 0.2f * e;
        float alpha = __expf(e - mh) * rsh;
        bf16x4 hv = *(const bf16x4*)(hw + (long)s * HID + c0);
        acc0 += alpha * bf2f(hv[0]); acc1 += alpha * bf2f(hv[1]);
        acc2 += alpha * bf2f(hv[2]); acc3 += alpha * bf2f(hv[3]);
    }
    // fused bias + LN + relu
    f32x4 bi = *(const f32x4*)(bias + c0);
    acc0 += bi[0]; acc1 += bi[1]; acc2 += bi[2]; acc3 += bi[3];
    float mean = wred(acc0 + acc1 + acc2 + acc3) * (1.f / 256.f);
    acc0 -= mean; acc1 -= mean; acc2 -= mean; acc3 -= mean;
    float var = wred(acc0 * acc0 + acc1 * acc1 + acc2 * acc2 + acc3 * acc3) * (1.f / 256.f);
    float inv = rsqrtf(var + 1e-5f);
    f32x4 gv = *(const f32x4*)(g + c0);
    f32x4 bv = *(const f32x4*)(b + c0);
    __hip_bfloat16 t0 = __float2bfloat16(fmaxf(acc0 * inv * gv[0] + bv[0], 0.f));
    __hip_bfloat16 t1 = __float2bfloat16(fmaxf(acc1 * inv * gv[1] + bv[1], 0.f));
    __hip_bfloat16 t2 = __float2bfloat16(fmaxf(acc2 * inv * gv[2] + bv[2], 0.f));
    __hip_bfloat16 t3 = __float2bfloat16(fmaxf(acc3 * inv * gv[3] + bv[3], 0.f));
    __hip_bfloat16* orow = out + d * HID + c0;
    orow[0] = t0; orow[1] = t1; orow[2] = t2; orow[3] = t3;
}

// ---------------- final: +bf -> LN(128) -> L2 normalize -> f32 out ----------------
__global__ __launch_bounds__(256) void final_ln_norm(
    const float* __restrict__ tmp, const float* __restrict__ bfv,
    const float* __restrict__ g, const float* __restrict__ b,
    float* __restrict__ out, int N) {
    int lane = threadIdx.x & 63;
    long row = (long)blockIdx.x * 4 + (threadIdx.x >> 6);
    if (row >= N) return;
    float v0 = tmp[row * 128 + lane] + bfv[lane];
    float v1 = tmp[row * 128 + 64 + lane] + bfv[64 + lane];
    float mean = wred(v0 + v1) * (1.f / 128.f);
    v0 -= mean; v1 -= mean;
    float var = wred(v0 * v0 + v1 * v1) * (1.f / 128.f);
    float inv = rsqrtf(var + 1e-5f);
    float y0 = v0 * inv * g[lane] + b[lane];
    float y1 = v1 * inv * g[64 + lane] + b[64 + lane];
    float nrm = sqrtf(wred(y0 * y0 + y1 * y1));
    float sc = 1.f / fmaxf(nrm, 1e-12f);
    out[row * 128 + lane] = y0 * sc;
    out[row * 128 + 64 + lane] = y1 * sc;
}

extern "C" void kernel_launch(void* const* d_in, const int* in_sizes, int n_in,
                              void* d_out, int out_size, void* d_ws, size_t ws_size,
                              hipStream_t stream) {
    const float* x      = (const float*)d_in[0];
    const int*   ei_bu  = (const int*)d_in[1];
    const int*   ei_td  = (const int*)d_in[2];
    const float* Wp     = (const float*)d_in[3];
    const float* bp     = (const float*)d_in[4];
    const float* W_bu   = (const float*)d_in[5];
    const float* asrc_bu= (const float*)d_in[6];
    const float* adst_bu= (const float*)d_in[7];
    const float* bias_bu= (const float*)d_in[8];
    const float* W_td   = (const float*)d_in[9];
    const float* asrc_td= (const float*)d_in[10];
    const float* adst_td= (const float*)d_in[11];
    const float* bias_td= (const float*)d_in[12];
    const float* Wf     = (const float*)d_in[13];
    const float* bfv    = (const float*)d_in[14];
    const float* g_bu   = (const float*)d_in[15];
    const float* b_bu   = (const float*)d_in[16];
    const float* g_td   = (const float*)d_in[17];
    const float* b_td   = (const float*)d_in[18];
    const float* g_out  = (const float*)d_in[19];
    const float* b_out  = (const float*)d_in[20];

    const int N = in_sizes[0] / HID;   // 200000
    const int E = in_sizes[1] / 2;     // 200000

    char* ws = (char*)d_ws;
    size_t off0 = 0;
    auto take = [&](size_t bytes) -> char* {
        char* p = ws + off0;
        off0 += (bytes + 255) & ~(size_t)255;
        return p;
    };
    __hip_bfloat16* xbf   = (__hip_bfloat16*)take((size_t)N * HID * 2); // aliased as hw later
    __hip_bfloat16* h_buf = (__hip_bfloat16*)take((size_t)N * HID * 2);
    __hip_bfloat16* xbu   = (__hip_bfloat16*)take((size_t)N * HID * 2);
    __hip_bfloat16* xtd   = (__hip_bfloat16*)take((size_t)N * HID * 2);
    float* tmp   = (float*)take((size_t)N * 128 * 4);   // final GEMM f32 out
    float* a_s   = (float*)take((size_t)N * 16);
    float* a_d   = (float*)take((size_t)N * 16);
    int* cnt     = (int*)take((size_t)N * 4);
    int* offpart = (int*)take((size_t)N * 4);
    int* offarr  = (int*)take((size_t)(N + 1) * 4);
    int* cur     = (int*)take((size_t)N * 4);
    int* esrc    = (int*)take((size_t)E * 4);
    int* bsum    = (int*)take(1024 * 4);
    int* btot    = (int*)take(1024 * 4);
    __hip_bfloat16* Wpt  = (__hip_bfloat16*)take(256 * 256 * 2);
    __hip_bfloat16* Wbut = (__hip_bfloat16*)take(256 * 256 * 2);
    __hip_bfloat16* Wtdt = (__hip_bfloat16*)take(256 * 256 * 2);
    __hip_bfloat16* Wft  = (__hip_bfloat16*)take(512 * 128 * 2);
    __hip_bfloat16* hw = xbf;  // xbf dead after first GEMM

    transpose_w<<<(256 * 256 + 255) / 256, 256, 0, stream>>>(Wp, Wpt, 256, 256);
    transpose_w<<<(256 * 256 + 255) / 256, 256, 0, stream>>>(W_bu, Wbut, 256, 256);
    transpose_w<<<(256 * 256 + 255) / 256, 256, 0, stream>>>(W_td, Wtdt, 256, 256);
    transpose_w<<<(512 * 128 + 255) / 256, 256, 0, stream>>>(Wf, Wft, 512, 128);
    long nx = (long)N * HID;
    cvt_bf16<<<(nx + 255) / 256, 256, 0, stream>>>(x, xbf, nx);

    int gm = (N + 127) / 128;   // 1563 row-blocks; BN = full output width

    // h = relu(x @ Wp + bp)
    gemm_tiled<256><<<gm, 512, 0, stream>>>(xbf, xbf, HID, HID, Wpt, HID,
                                            bp, 1, h_buf, nullptr, N);

    const int* eis[2] = {ei_bu, ei_td};
    const __hip_bfloat16* Wts[2] = {Wbut, Wtdt};
    const float* asrcs[2] = {asrc_bu, asrc_td};
    const float* adsts[2] = {adst_bu, adst_td};
    const float* biases[2]= {bias_bu, bias_td};
    const float* gs[2]    = {g_bu, g_td};
    const float* bs[2]    = {b_bu, b_td};
    __hip_bfloat16* xouts[2] = {xbu, xtd};

    int egrid = (E + 255) / 256;
    int ngrid = (N + 255) / 256;
    int nb = (N + 255) / 256;
    for (int dir = 0; dir < 2; ++dir) {
        gemm_tiled<256><<<gm, 512, 0, stream>>>(h_buf, h_buf, HID, HID, Wts[dir], HID,
                                                nullptr, 0, hw, nullptr, N);
        att_scores<<<(N + 3) / 4, 256, 0, stream>>>(hw, asrcs[dir], adsts[dir], a_s, a_d, N);
        // CSR build
        hipMemsetAsync(cnt, 0, (size_t)N * 4, stream);
        hipMemsetAsync(cur, 0, (size_t)N * 4, stream);
        hist_dst<<<egrid, 256, 0, stream>>>(eis[dir], E, cnt);
        scan1<<<nb, 256, 0, stream>>>(cnt, offpart, bsum, N);
        scan2<<<1, 256, 0, stream>>>(bsum, btot, nb);
        finalize_off<<<ngrid, 256, 0, stream>>>(offpart, btot, offarr, N, E);
        scatter_src<<<egrid, 256, 0, stream>>>(eis[dir], E, offarr, cur, esrc);
        // fused GAT + bias + LN + relu
        gat_fused<<<(N + 3) / 4, 256, 0, stream>>>(offarr, esrc, a_s, a_d, hw,
                                                   biases[dir], gs[dir], bs[dir],
                                                   xouts[dir], N);
    }

    // final: tmp = [xbu|xtd] @ Wf (f32), then +bf -> LN -> L2norm -> out
    gemm_tiled<128><<<gm, 512, 0, stream>>>(xbu, xtd, HID, HID, Wft, 512,
                                            nullptr, 0, nullptr, tmp, N);
    final_ln_norm<<<(N + 3) / 4, 256, 0, stream>>>(tmp, bfv, g_out, b_out,
                                                   (float*)d_out, N);
}

// Round 3
// 996.205 us; speedup vs baseline: 1.9706x; 1.2809x over previous
//
#include <hip/hip_runtime.h>
#include <hip/hip_bf16.h>
#include <stdint.h>

// HierarchicalGNN forward, FP32 in/out, MFMA bf16 GEMMs, CSR-gather GAT (no f32 atomics).
// h=relu(x@Wp+bp); two GATConv(+selfloops, softmax-per-dst) -> LN -> relu;
// concat @ Wf -> LN -> L2-normalize.
// N=200000, E=200000/dir (avg degree ~1 -> thread-per-node softmax), IN=HID=256, HEADS=4, C=64, OUT=128.

typedef __attribute__((ext_vector_type(8))) short bf16x8;
typedef __attribute__((ext_vector_type(4))) short bf16x4;
typedef __attribute__((ext_vector_type(4))) float f32x4;

#define HID 256
#define HEADS 4
#define CH 64

__device__ __forceinline__ float wred(float v) {
    #pragma unroll
    for (int o = 32; o > 0; o >>= 1) v += __shfl_xor(v, o, 64);
    return v;
}
__device__ __forceinline__ float bf2f(short s) {
    return __uint_as_float(((unsigned)(unsigned short)s) << 16);
}

// async global->LDS, 16B per lane (global_load_lds_dwordx4).
__device__ __forceinline__ void gload_lds16(const void* g, void* l) {
    __builtin_amdgcn_global_load_lds(
        reinterpret_cast<const __attribute__((address_space(1))) uint32_t*>(
            reinterpret_cast<uintptr_t>(g)),
        reinterpret_cast<__attribute__((address_space(3))) uint32_t*>(
            reinterpret_cast<uintptr_t>(l)),
        16, 0, 0);
}

// ---------------- f32 -> bf16 convert (x4 vectorized) ----------------
__global__ __launch_bounds__(256) void cvt_bf16(const float* __restrict__ src,
                                                __hip_bfloat16* __restrict__ dst, long n4) {
    long i = (long)blockIdx.x * 256 + threadIdx.x;   // i indexes groups of 4
    if (i >= n4) return;
    f32x4 v = *(const f32x4*)(src + i * 4);
    __hip_bfloat16 o[4];
    o[0] = __float2bfloat16(v[0]);
    o[1] = __float2bfloat16(v[1]);
    o[2] = __float2bfloat16(v[2]);
    o[3] = __float2bfloat16(v[3]);
    *(bf16x4*)((short*)dst + i * 4) = *(const bf16x4*)o;
}

// ---------------- transpose+convert W[KI,KO] f32 -> Wt[KO,KI] bf16 ----------------
__global__ void transpose_w(const float* __restrict__ W,
                            __hip_bfloat16* __restrict__ Wt, int KI, int KO) {
    int idx = blockIdx.x * 256 + threadIdx.x;
    if (idx >= KI * KO) return;
    int k = idx / KO, j = idx % KO;
    Wt[(long)j * KI + k] = __float2bfloat16(W[idx]);
}

// ---------------- tiled MFMA GEMM: C[N,BN] = A[N,KI] @ Bt[BN,KI]^T ----------------
// m97 structure: BM=128, BK=32, LDS-staged A/B via global_load_lds_dwordx4,
// 2 barriers per K-step. BN = full output width so A is fetched once.
template<int BN>
__global__ __launch_bounds__(512) void gemm_tiled(
    const __hip_bfloat16* __restrict__ A0, const __hip_bfloat16* __restrict__ A1,
    int lda, int kSplit,
    const __hip_bfloat16* __restrict__ Bt, int KI,
    const float* __restrict__ bias, int doRelu,
    __hip_bfloat16* __restrict__ outB, float* __restrict__ outF, int N) {

    constexpr int WN = BN / 64;          // waves along N (4 or 2)
    constexpr int WM = 8 / WN;           // waves along M (2 or 4)
    constexpr int MR = (128 / WM) / 16;  // m-frags per wave (4 or 2)

    __shared__ __align__(16) __hip_bfloat16 sA[128 * 32];   // [row][k] 64B rows
    __shared__ __align__(16) __hip_bfloat16 sB[BN * 32];    // [col][k] 64B rows

    int tid = threadIdx.x;
    int wv = tid >> 6, ln = tid & 63;
    int m = ln & 15, q = ln >> 4;
    long row0 = (long)blockIdx.x * 128;
    int wr = (wv / WN) * (128 / WM);
    int wc = (wv % WN) * 64;

    f32x4 acc[MR][4];
    #pragma unroll
    for (int mi = 0; mi < MR; ++mi)
        #pragma unroll
        for (int t = 0; t < 4; ++t) acc[mi][t] = (f32x4){0.f, 0.f, 0.f, 0.f};

    int oA = tid * 16;
    long rowA = row0 + (oA >> 6);
    if (rowA >= N) rowA = N - 1;         // clamp tail loads (dup reads, safe)
    long aOff = rowA * lda + ((oA & 63) >> 1);

    for (int k0 = 0; k0 < KI; k0 += 32) {
        const __hip_bfloat16* Ab = (k0 < kSplit) ? A0 + k0 : A1 + (k0 - kSplit);
        __syncthreads();
        gload_lds16(Ab + aOff, (char*)sA + oA);
        #pragma unroll
        for (int j = 0; j < BN / 128; ++j) {
            int o = j * 8192 + tid * 16;
            const __hip_bfloat16* src = Bt + (long)(o >> 6) * KI + k0 + ((o & 63) >> 1);
            gload_lds16(src, (char*)sB + o);
        }
        __syncthreads();

        bf16x8 af[MR], bfr[4];
        #pragma unroll
        for (int mi = 0; mi < MR; ++mi)
            af[mi] = *(const bf16x8*)((const char*)sA + ((wr + mi * 16 + m) << 6) + q * 16);
        #pragma unroll
        for (int t = 0; t < 4; ++t)
            bfr[t] = *(const bf16x8*)((const char*)sB + ((wc + t * 16 + m) << 6) + q * 16);
        #pragma unroll
        for (int mi = 0; mi < MR; ++mi)
            #pragma unroll
            for (int t = 0; t < 4; ++t)
                acc[mi][t] = __builtin_amdgcn_mfma_f32_16x16x32_bf16(af[mi], bfr[t],
                                                                     acc[mi][t], 0, 0, 0);
    }

    #pragma unroll
    for (int mi = 0; mi < MR; ++mi) {
        #pragma unroll
        for (int t = 0; t < 4; ++t) {
            int col = wc + t * 16 + m;
            float bv = bias ? bias[col] : 0.f;
            #pragma unroll
            for (int r = 0; r < 4; ++r) {
                long row = row0 + wr + mi * 16 + q * 4 + r;
                if (row < N) {
                    float v = acc[mi][t][r] + bv;
                    if (doRelu) v = fmaxf(v, 0.f);
                    if (outB) outB[row * BN + col] = __float2bfloat16(v);
                    else      outF[row * BN + col] = v;
                }
            }
        }
    }
}

// ---------------- attention scores: a_src/a_dst [N,4] ----------------
// wave per node; lane holds 4 channels (c0=lane*4, head=lane>>4); 16-lane segmented reduce.
__global__ __launch_bounds__(256) void att_scores(
    const __hip_bfloat16* __restrict__ hw,
    const float* __restrict__ asrc, const float* __restrict__ adst,
    float* __restrict__ a_s, float* __restrict__ a_d, int N) {
    int lane = threadIdx.x & 63;
    long node = (long)blockIdx.x * 4 + (threadIdx.x >> 6);
    if (node >= N) return;
    int c0 = lane * 4;
    bf16x4 hv = *(const bf16x4*)(hw + node * HID + c0);
    f32x4 sv = *(const f32x4*)(asrc + c0);   // [HEADS][CH] flat == channel index
    f32x4 dv = *(const f32x4*)(adst + c0);
    float ps = bf2f(hv[0]) * sv[0] + bf2f(hv[1]) * sv[1]
             + bf2f(hv[2]) * sv[2] + bf2f(hv[3]) * sv[3];
    float pd = bf2f(hv[0]) * dv[0] + bf2f(hv[1]) * dv[1]
             + bf2f(hv[2]) * dv[2] + bf2f(hv[3]) * dv[3];
    #pragma unroll
    for (int o = 8; o > 0; o >>= 1) {
        ps += __shfl_xor(ps, o, 64);
        pd += __shfl_xor(pd, o, 64);
    }
    if ((lane & 15) == 0) {
        a_s[node * 4 + (lane >> 4)] = ps;
        a_d[node * 4 + (lane >> 4)] = pd;
    }
}

// ---------------- CSR build ----------------
__global__ __launch_bounds__(256) void hist_dst(const int* __restrict__ ei, int E,
                                                int* __restrict__ cnt) {
    int e = blockIdx.x * 256 + threadIdx.x;
    if (e < E) atomicAdd(&cnt[ei[E + e]], 1);
}

__global__ __launch_bounds__(256) void scan1(const int* __restrict__ cnt,
                                             int* __restrict__ offpart,
                                             int* __restrict__ bsum, int n) {
    int t = threadIdx.x, i = blockIdx.x * 256 + t;
    int lane = t & 63, w = t >> 6;
    int v = (i < n) ? cnt[i] : 0;
    int inc = v;
    #pragma unroll
    for (int o = 1; o < 64; o <<= 1) {
        int u = __shfl_up(inc, o, 64);
        if (lane >= o) inc += u;
    }
    __shared__ int wsum[4];
    if (lane == 63) wsum[w] = inc;
    __syncthreads();
    int wadd = 0;
    #pragma unroll
    for (int k = 0; k < 4; ++k) if (k < w) wadd += wsum[k];
    if (i < n) offpart[i] = inc - v + wadd;
    if (t == 255) bsum[blockIdx.x] = inc + wadd;
}

__global__ __launch_bounds__(256) void scan2(const int* __restrict__ bsum,
                                             int* __restrict__ btot, int nb) {
    int t = threadIdx.x, lane = t & 63, w = t >> 6;
    int loc[4]; int s = 0;
    #pragma unroll
    for (int k = 0; k < 4; ++k) {
        int idx = t * 4 + k;
        int v = (idx < nb) ? bsum[idx] : 0;
        loc[k] = s; s += v;
    }
    int inc = s;
    #pragma unroll
    for (int o = 1; o < 64; o <<= 1) {
        int u = __shfl_up(inc, o, 64);
        if (lane >= o) inc += u;
    }
    __shared__ int wsum[4];
    if (lane == 63) wsum[w] = inc;
    __syncthreads();
    int wadd = 0;
    #pragma unroll
    for (int k = 0; k < 4; ++k) if (k < w) wadd += wsum[k];
    int excl = inc - s + wadd;
    #pragma unroll
    for (int k = 0; k < 4; ++k) {
        int idx = t * 4 + k;
        if (idx < nb) btot[idx] = excl + loc[k];
    }
}

__global__ __launch_bounds__(256) void finalize_off(const int* __restrict__ offpart,
                                                    const int* __restrict__ btot,
                                                    int* __restrict__ off, int n, int E) {
    int i = blockIdx.x * 256 + threadIdx.x;
    if (i < n) off[i] = offpart[i] + btot[i >> 8];
    if (i == 0) off[n] = E;
}

__global__ __launch_bounds__(256) void scatter_src(const int* __restrict__ ei, int E,
                                                   const int* __restrict__ off,
                                                   int* __restrict__ cur,
                                                   int* __restrict__ esrc) {
    int e = blockIdx.x * 256 + threadIdx.x;
    if (e >= E) return;
    int d = ei[E + e];
    int pos = off[d] + atomicAdd(&cur[d], 1);
    esrc[pos] = ei[e];
}

// ---------------- per-dst softmax -> alpha (thread per node; avg degree ~1) ----------------
__global__ __launch_bounds__(256) void att_alpha(
    const int* __restrict__ off, const int* __restrict__ esrc,
    const float* __restrict__ a_s, const float* __restrict__ a_d,
    float* __restrict__ alpha_self, float* __restrict__ alpha_e, int N) {
    int d = blockIdx.x * 256 + threadIdx.x;
    if (d >= N) return;
    int beg = off[d], end = off[d + 1];
    f32x4 adv = *(const f32x4*)(a_d + 4 * (long)d);
    f32x4 asd = *(const f32x4*)(a_s + 4 * (long)d);
    float es[4], m[4];
    #pragma unroll
    for (int h = 0; h < 4; ++h) {
        float e = asd[h] + adv[h]; e = e > 0.f ? e : 0.2f * e;
        es[h] = e; m[h] = e;
    }
    for (int j = beg; j < end; ++j) {
        int s = esrc[j];
        f32x4 asv = *(const f32x4*)(a_s + 4 * (long)s);
        #pragma unroll
        for (int h = 0; h < 4; ++h) {
            float e = asv[h] + adv[h]; e = e > 0.f ? e : 0.2f * e;
            m[h] = fmaxf(m[h], e);
        }
    }
    float sum[4];
    #pragma unroll
    for (int h = 0; h < 4; ++h) sum[h] = __expf(es[h] - m[h]);
    for (int j = beg; j < end; ++j) {
        int s = esrc[j];
        f32x4 asv = *(const f32x4*)(a_s + 4 * (long)s);
        #pragma unroll
        for (int h = 0; h < 4; ++h) {
            float e = asv[h] + adv[h]; e = e > 0.f ? e : 0.2f * e;
            sum[h] += __expf(e - m[h]);
        }
    }
    float rs[4];
    #pragma unroll
    for (int h = 0; h < 4; ++h) rs[h] = 1.f / sum[h];
    f32x4 sa;
    #pragma unroll
    for (int h = 0; h < 4; ++h) sa[h] = __expf(es[h] - m[h]) * rs[h];
    *(f32x4*)(alpha_self + 4 * (long)d) = sa;
    for (int j = beg; j < end; ++j) {
        int s = esrc[j];
        f32x4 asv = *(const f32x4*)(a_s + 4 * (long)s);
        f32x4 av;
        #pragma unroll
        for (int h = 0; h < 4; ++h) {
            float e = asv[h] + adv[h]; e = e > 0.f ? e : 0.2f * e;
            av[h] = __expf(e - m[h]) * rs[h];
        }
        *(f32x4*)(alpha_e + 4 * (long)j) = av;
    }
}

// ---------------- gather + bias + LN + relu (wave per dst node) ----------------
__global__ __launch_bounds__(256) void gat_gather(
    const int* __restrict__ off, const int* __restrict__ esrc,
    const float* __restrict__ alpha_self, const float* __restrict__ alpha_e,
    const __hip_bfloat16* __restrict__ hw,
    const float* __restrict__ bias, const float* __restrict__ g,
    const float* __restrict__ b,
    __hip_bfloat16* __restrict__ out, int N) {
    int lane = threadIdx.x & 63;
    long d = (long)blockIdx.x * 4 + (threadIdx.x >> 6);
    if (d >= N) return;
    int beg = off[d], end = off[d + 1];
    int h4 = lane >> 4;
    int c0 = lane * 4;
    float acc0, acc1, acc2, acc3;
    {   // self loop
        float a = alpha_self[4 * d + h4];
        bf16x4 hv = *(const bf16x4*)(hw + d * HID + c0);
        acc0 = a * bf2f(hv[0]); acc1 = a * bf2f(hv[1]);
        acc2 = a * bf2f(hv[2]); acc3 = a * bf2f(hv[3]);
    }
    for (int j = beg; j < end; ++j) {
        int s = esrc[j];                       // uniform across wave
        float a = alpha_e[4 * (long)j + h4];   // broadcast within 16-lane group
        bf16x4 hv = *(const bf16x4*)(hw + (long)s * HID + c0);
        acc0 += a * bf2f(hv[0]); acc1 += a * bf2f(hv[1]);
        acc2 += a * bf2f(hv[2]); acc3 += a * bf2f(hv[3]);
    }
    // fused bias + LN + relu
    f32x4 bi = *(const f32x4*)(bias + c0);
    acc0 += bi[0]; acc1 += bi[1]; acc2 += bi[2]; acc3 += bi[3];
    float mean = wred(acc0 + acc1 + acc2 + acc3) * (1.f / 256.f);
    acc0 -= mean; acc1 -= mean; acc2 -= mean; acc3 -= mean;
    float var = wred(acc0 * acc0 + acc1 * acc1 + acc2 * acc2 + acc3 * acc3) * (1.f / 256.f);
    float inv = rsqrtf(var + 1e-5f);
    f32x4 gv = *(const f32x4*)(g + c0);
    f32x4 bv = *(const f32x4*)(b + c0);
    __hip_bfloat16 t0 = __float2bfloat16(fmaxf(acc0 * inv * gv[0] + bv[0], 0.f));
    __hip_bfloat16 t1 = __float2bfloat16(fmaxf(acc1 * inv * gv[1] + bv[1], 0.f));
    __hip_bfloat16 t2 = __float2bfloat16(fmaxf(acc2 * inv * gv[2] + bv[2], 0.f));
    __hip_bfloat16 t3 = __float2bfloat16(fmaxf(acc3 * inv * gv[3] + bv[3], 0.f));
    __hip_bfloat16* orow = out + d * HID + c0;
    orow[0] = t0; orow[1] = t1; orow[2] = t2; orow[3] = t3;
}

// ---------------- final: +bf -> LN(128) -> L2 normalize -> f32 out ----------------
__global__ __launch_bounds__(256) void final_ln_norm(
    const float* __restrict__ tmp, const float* __restrict__ bfv,
    const float* __restrict__ g, const float* __restrict__ b,
    float* __restrict__ out, int N) {
    int lane = threadIdx.x & 63;
    long row = (long)blockIdx.x * 4 + (threadIdx.x >> 6);
    if (row >= N) return;
    float v0 = tmp[row * 128 + lane] + bfv[lane];
    float v1 = tmp[row * 128 + 64 + lane] + bfv[64 + lane];
    float mean = wred(v0 + v1) * (1.f / 128.f);
    v0 -= mean; v1 -= mean;
    float var = wred(v0 * v0 + v1 * v1) * (1.f / 128.f);
    float inv = rsqrtf(var + 1e-5f);
    float y0 = v0 * inv * g[lane] + b[lane];
    float y1 = v1 * inv * g[64 + lane] + b[64 + lane];
    float nrm = sqrtf(wred(y0 * y0 + y1 * y1));
    float sc = 1.f / fmaxf(nrm, 1e-12f);
    out[row * 128 + lane] = y0 * sc;
    out[row * 128 + 64 + lane] = y1 * sc;
}

extern "C" void kernel_launch(void* const* d_in, const int* in_sizes, int n_in,
                              void* d_out, int out_size, void* d_ws, size_t ws_size,
                              hipStream_t stream) {
    const float* x      = (const float*)d_in[0];
    const int*   ei_bu  = (const int*)d_in[1];
    const int*   ei_td  = (const int*)d_in[2];
    const float* Wp     = (const float*)d_in[3];
    const float* bp     = (const float*)d_in[4];
    const float* W_bu   = (const float*)d_in[5];
    const float* asrc_bu= (const float*)d_in[6];
    const float* adst_bu= (const float*)d_in[7];
    const float* bias_bu= (const float*)d_in[8];
    const float* W_td   = (const float*)d_in[9];
    const float* asrc_td= (const float*)d_in[10];
    const float* adst_td= (const float*)d_in[11];
    const float* bias_td= (const float*)d_in[12];
    const float* Wf     = (const float*)d_in[13];
    const float* bfv    = (const float*)d_in[14];
    const float* g_bu   = (const float*)d_in[15];
    const float* b_bu   = (const float*)d_in[16];
    const float* g_td   = (const float*)d_in[17];
    const float* b_td   = (const float*)d_in[18];
    const float* g_out  = (const float*)d_in[19];
    const float* b_out  = (const float*)d_in[20];

    const int N = in_sizes[0] / HID;   // 200000
    const int E = in_sizes[1] / 2;     // 200000

    char* ws = (char*)d_ws;
    size_t off0 = 0;
    auto take = [&](size_t bytes) -> char* {
        char* p = ws + off0;
        off0 += (bytes + 255) & ~(size_t)255;
        return p;
    };
    __hip_bfloat16* xbf   = (__hip_bfloat16*)take((size_t)N * HID * 2); // aliased as hw later
    __hip_bfloat16* h_buf = (__hip_bfloat16*)take((size_t)N * HID * 2);
    __hip_bfloat16* xbu   = (__hip_bfloat16*)take((size_t)N * HID * 2);
    __hip_bfloat16* xtd   = (__hip_bfloat16*)take((size_t)N * HID * 2);
    float* tmp   = (float*)take((size_t)N * 128 * 4);   // final GEMM f32 out
    float* a_s   = (float*)take((size_t)N * 16);
    float* a_d   = (float*)take((size_t)N * 16);
    float* alsf  = (float*)take((size_t)N * 16);        // alpha_self [N][4]
    float* ale   = (float*)take((size_t)E * 16);        // alpha_e [E][4] (CSR order)
    int* cnt     = (int*)take((size_t)N * 4);
    int* offpart = (int*)take((size_t)N * 4);
    int* offarr  = (int*)take((size_t)(N + 1) * 4);
    int* cur     = (int*)take((size_t)N * 4);
    int* esrc    = (int*)take((size_t)E * 4);
    int* bsum    = (int*)take(1024 * 4);
    int* btot    = (int*)take(1024 * 4);
    __hip_bfloat16* Wpt  = (__hip_bfloat16*)take(256 * 256 * 2);
    __hip_bfloat16* Wbut = (__hip_bfloat16*)take(256 * 256 * 2);
    __hip_bfloat16* Wtdt = (__hip_bfloat16*)take(256 * 256 * 2);
    __hip_bfloat16* Wft  = (__hip_bfloat16*)take(512 * 128 * 2);
    __hip_bfloat16* hw = xbf;  // xbf dead after first GEMM

    transpose_w<<<(256 * 256 + 255) / 256, 256, 0, stream>>>(Wp, Wpt, 256, 256);
    transpose_w<<<(256 * 256 + 255) / 256, 256, 0, stream>>>(W_bu, Wbut, 256, 256);
    transpose_w<<<(256 * 256 + 255) / 256, 256, 0, stream>>>(W_td, Wtdt, 256, 256);
    transpose_w<<<(512 * 128 + 255) / 256, 256, 0, stream>>>(Wf, Wft, 512, 128);
    long nx4 = (long)N * HID / 4;
    cvt_bf16<<<(nx4 + 255) / 256, 256, 0, stream>>>(x, xbf, nx4);

    int gm = (N + 127) / 128;

    // h = relu(x @ Wp + bp)
    gemm_tiled<256><<<gm, 512, 0, stream>>>(xbf, xbf, HID, HID, Wpt, HID,
                                            bp, 1, h_buf, nullptr, N);

    const int* eis[2] = {ei_bu, ei_td};
    const __hip_bfloat16* Wts[2] = {Wbut, Wtdt};
    const float* asrcs[2] = {asrc_bu, asrc_td};
    const float* adsts[2] = {adst_bu, adst_td};
    const float* biases[2]= {bias_bu, bias_td};
    const float* gs[2]    = {g_bu, g_td};
    const float* bs[2]    = {b_bu, b_td};
    __hip_bfloat16* xouts[2] = {xbu, xtd};

    int egrid = (E + 255) / 256;
    int ngrid = (N + 255) / 256;
    int nb = (N + 255) / 256;
    for (int dir = 0; dir < 2; ++dir) {
        gemm_tiled<256><<<gm, 512, 0, stream>>>(h_buf, h_buf, HID, HID, Wts[dir], HID,
                                                nullptr, 0, hw, nullptr, N);
        att_scores<<<(N + 3) / 4, 256, 0, stream>>>(hw, asrcs[dir], adsts[dir], a_s, a_d, N);
        // CSR build
        hipMemsetAsync(cnt, 0, (size_t)N * 4, stream);
        hipMemsetAsync(cur, 0, (size_t)N * 4, stream);
        hist_dst<<<egrid, 256, 0, stream>>>(eis[dir], E, cnt);
        scan1<<<nb, 256, 0, stream>>>(cnt, offpart, bsum, N);
        scan2<<<1, 256, 0, stream>>>(bsum, btot, nb);
        finalize_off<<<ngrid, 256, 0, stream>>>(offpart, btot, offarr, N, E);
        scatter_src<<<egrid, 256, 0, stream>>>(eis[dir], E, offarr, cur, esrc);
        // softmax (thread per node) then gather + bias + LN + relu (wave per node)
        att_alpha<<<ngrid, 256, 0, stream>>>(offarr, esrc, a_s, a_d, alsf, ale, N);
        gat_gather<<<(N + 3) / 4, 256, 0, stream>>>(offarr, esrc, alsf, ale, hw,
                                                    biases[dir], gs[dir], bs[dir],
                                                    xouts[dir], N);
    }

    // final: tmp = [xbu|xtd] @ Wf (f32), then +bf -> LN -> L2norm -> out
    gemm_tiled<128><<<gm, 512, 0, stream>>>(xbu, xtd, HID, HID, Wft, 512,
                                            nullptr, 0, nullptr, tmp, N);
    final_ln_norm<<<(N + 3) / 4, 256, 0, stream>>>(tmp, bfv, g_out, b_out,
                                                   (float*)d_out, N);
}